// Round 6
// baseline (364.965 us; speedup 1.0000x reference)
//
#include <hip/hip_runtime.h>
#include <hip/hip_bf16.h>

// ---------------- problem constants ----------------
constexpr int BATCH = 8;
constexpr int CIN   = 256;
constexpr int HH    = 64;
constexpr int WW    = 64;
constexpr int NPIX  = HH * WW;        // 4096
constexpr int ICH   = 128;            // init_ch == new_ch

// ---------------- workspace layout (in floats) ----------------
constexpr size_t OFF_XD    = 0;                        // 8*256*16*16 = 524288 f
constexpr size_t OFF_HMEAN = 524288;                   // 256 f
constexpr size_t OFF_WFULL = 524544;                   // 64 f
constexpr size_t OFF_SLOT  = 524608;                   // 64 f (ints)
constexpr size_t OFF_WTB   = 524672;                   // bf16 weights: 1,474,560 us = 737,280 f
constexpr size_t OFF_XBP   = OFF_WTB + 737280;         // bf16 x padded NHWC 8*66*66*256 us = 4,460,544 f
constexpr size_t OFF_X1B   = OFF_XBP + 4460544;        // bf16 x1: 12,582,912 us = 6,291,456 f
// total = 12,013,952 floats = 48.1 MB of d_ws (round-3 proved >= 58.3 MB available)

typedef __bf16  bf16x8 __attribute__((ext_vector_type(8)));
typedef float   f32x4  __attribute__((ext_vector_type(4)));

__device__ __forceinline__ float silu_f(float v) { return v / (1.f + __expf(-v)); }

__device__ __forceinline__ unsigned short f2bf(float f) {
    return __builtin_bit_cast(unsigned short, __float2bfloat16(f));
}
__device__ __forceinline__ float bf2f(unsigned short u) {
    return __builtin_bit_cast(float, (unsigned)u << 16);
}
__device__ __forceinline__ bf16x8 ld_frag(const ushort* p) {
    uint4 v = *(const uint4*)p;          // ds_read_b128 / global_load_dwordx4
    return __builtin_bit_cast(bf16x8, v);
}
// async global->LDS DMA, 16B per lane; LDS dest = wave-uniform base + lane*16
__device__ __forceinline__ void gload16(const ushort* g, ushort* l) {
    __builtin_amdgcn_global_load_lds(
        (const __attribute__((address_space(1))) void*)g,
        (__attribute__((address_space(3))) void*)l, 16, 0, 0);
}

// ---------------- K1: 4x4 avg pool  x[8,256,64,64] -> xd[8,256,16,16] ----------------
__global__ void k_avgpool(const float* __restrict__ x, float* __restrict__ xd)
{
    int t = blockIdx.x * 256 + threadIdx.x;
    int jb = t & 3, i = (t >> 2) & 15, c = (t >> 6) & 255, b = t >> 14;
    const float* src = x + ((size_t)(b * CIN + c) * HH + i * 4) * WW + jb * 16;
    float s0 = 0.f, s1 = 0.f, s2 = 0.f, s3 = 0.f;
#pragma unroll
    for (int r = 0; r < 4; ++r) {
        const float4* p = (const float4*)(src + r * WW);
        float4 a = p[0], b4 = p[1], c4 = p[2], d4 = p[3];
        s0 += a.x + a.y + a.z + a.w;
        s1 += b4.x + b4.y + b4.z + b4.w;
        s2 += c4.x + c4.y + c4.z + c4.w;
        s3 += d4.x + d4.y + d4.z + d4.w;
    }
    float4 o;
    o.x = s0 * 0.0625f; o.y = s1 * 0.0625f; o.z = s2 * 0.0625f; o.w = s3 * 0.0625f;
    *(float4*)(xd + ((size_t)(b * CIN + c) * 16 + i) * 16 + jb * 4) = o;
}

// ---------------- K1b: x fp32 NCHW -> bf16 padded NHWC [b][row+1][col+1][cin] --------
// interior only; borders are zeroed by an async memset before this kernel
__global__ __launch_bounds__(256) void k_xprep(const float* __restrict__ x,
                                               ushort* __restrict__ xbp)
{
    int b = blockIdx.x >> 6, row = blockIdx.x & 63;
    __shared__ ushort tile[64 * 258];    // [col][cin], pad 2 to break bank conflicts
    int tid = threadIdx.x;
    const float* src = x + ((size_t)b * CIN * HH + row) * WW;   // + cin*4096 + col
    for (int k = tid; k < 256 * 64; k += 256) {
        int cin = k >> 6, col = k & 63;                         // coalesced fp32 read
        tile[col * 258 + cin] = f2bf(src[(size_t)cin * NPIX + col]);
    }
    __syncthreads();
    ushort* dst = xbp + ((size_t)(b * 66 + row + 1) * 66 + 1) * 256;
    for (int k = tid; k < 64 * 128; k += 256) {
        int col = k >> 7, cp = (k & 127) * 2;
        unsigned u0 = tile[col * 258 + cp];
        unsigned u1 = tile[col * 258 + cp + 1];
        *(unsigned*)(dst + (size_t)col * 256 + cp) = u0 | (u1 << 16);  // coalesced
    }
}

// ---------------- K2: router conv3x3 (256->32) + BN + SiLU, mean over HW -------------
__global__ __launch_bounds__(256) void k_router_conv(
    const float* __restrict__ xd, const float* __restrict__ Wr1,
    const float* __restrict__ sr1, const float* __restrict__ br1,
    float* __restrict__ hmean)
{
    int b = blockIdx.x >> 5, r = blockIdx.x & 31;
    __shared__ float wl[9 * 256];
    __shared__ float red[256];
    int tid = threadIdx.x;
    for (int k = tid; k < 2304; k += 256) {
        int cin = k / 9, tap = k % 9;
        wl[tap * 256 + cin] = Wr1[r * 2304 + k];
    }
    __syncthreads();
    const float* xb = xd + (size_t)b * CIN * 256;
    int i = tid >> 4, j = tid & 15;
    float acc = 0.f;
#pragma unroll
    for (int kh = 0; kh < 3; ++kh) {
        int ii = i + kh - 1;
        bool oki = (unsigned)ii < 16u;
        int iis = oki ? ii : 0;
#pragma unroll
        for (int kw = 0; kw < 3; ++kw) {
            int jj = j + kw - 1;
            bool ok = oki && ((unsigned)jj < 16u);
            int off = iis * 16 + (((unsigned)jj < 16u) ? jj : 0);
            const float* wt = wl + (kh * 3 + kw) * 256;
            float t = 0.f;
#pragma unroll 8
            for (int cin = 0; cin < 256; ++cin)
                t = fmaf(wt[cin], xb[cin * 256 + off], t);
            if (ok) acc += t;
        }
    }
    float h = silu_f(acc * sr1[r] + br1[r]);
    red[tid] = h;
    __syncthreads();
    for (int st = 128; st > 0; st >>= 1) {
        if (tid < st) red[tid] += red[tid + st];
        __syncthreads();
    }
    if (tid == 0) hmean[b * 32 + r] = red[0] * (1.f / 256.f);
}

// ---------------- K3: router head: 1x1 conv + BN, softmax, top-k, slot compaction ----
__global__ void k_router_final(const float* __restrict__ hmean,
                               const float* __restrict__ Wr2, const float* __restrict__ sr2,
                               const float* __restrict__ br2, const int* __restrict__ topk_p,
                               float* __restrict__ wfull, int* __restrict__ slot)
{
    __shared__ float lg[8][4];
    __shared__ float wf[8][5];
    int tid = threadIdx.x;
    if (tid < 32) {
        int b = tid >> 2, e = tid & 3;
        float a = 0.f;
        for (int r = 0; r < 32; ++r) a += Wr2[e * 32 + r] * hmean[b * 32 + r];
        lg[b][e] = a * sr2[e] + br2[e];
    }
    __syncthreads();
    if (tid < 8) {
        int b = tid;
        float l0 = lg[b][0], l1 = lg[b][1], l2 = lg[b][2], l3 = lg[b][3];
        float mx = fmaxf(fmaxf(l0, l1), fmaxf(l2, l3));
        float e0 = __expf(l0 - mx), e1 = __expf(l1 - mx), e2 = __expf(l2 - mx), e3 = __expf(l3 - mx);
        float sum = e0 + e1 + e2 + e3;
        float w[4] = { e0 / sum, e1 / sum, e2 / sum, e3 / sum };
        int k = topk_p[0];
        if (k > 4) k = 4;
        bool taken[4] = { false, false, false, false };
        float tv[4]; int ti[4]; float tsum = 0.f;
        for (int t = 0; t < k; ++t) {
            float best = -1e30f; int bi = 0;
            for (int e = 0; e < 4; ++e)
                if (!taken[e] && w[e] > best) { best = w[e]; bi = e; }
            taken[bi] = true; tv[t] = best; ti[t] = bi; tsum += best;
        }
        float inv = 1.f / (tsum + 1e-6f);
        float o[4] = { 0.f, 0.f, 0.f, 0.f };
        for (int t = 0; t < k; ++t) o[ti[t]] = tv[t] * inv;
        for (int e = 0; e < 4; ++e) { wf[b][e] = o[e]; wfull[b * 5 + e] = o[e]; }
        wf[b][4] = 1.f; wfull[b * 5 + 4] = 1.f;
    }
    __syncthreads();
    if (tid == 0) {
        int cnt = 0;
        for (int s = 0; s < 5; ++s)
            for (int b = 0; b < 8; ++b)
                slot[s * 8 + b] = (wf[b][s] != 0.f) ? (cnt++) : -1;
    }
}

// ---------------- Kprep: weights fp32 OIHW -> bf16 [s][half][chunk][tap][oc64][ks][8] -
__global__ void k_wprep16(const float* __restrict__ We_p, const float* __restrict__ Ws_p,
                          ushort* __restrict__ wtb)
{
    int t = blockIdx.x * 256 + threadIdx.x;   // 1,474,560 dest-linear
    int k5  = t & 31;                          // ks*8+j = cin-in-chunk
    int oc  = (t >> 5) & 63;
    int tap = (t >> 11) % 9;
    int blk = t / 18432;                       // s*16 + h*8 + chunk
    int chunk = blk & 7;
    int h     = (blk >> 3) & 1;
    int s     = blk >> 4;
    int cin   = chunk * 32 + k5;
    int ocg   = h * 64 + oc;
    float v = (s < 4) ? We_p[((size_t)(s * 128 + ocg) * 256 + cin) * 9 + tap]
                      : Ws_p[((size_t)ocg * 256 + cin) * 9 + tap];
    wtb[t] = f2bf(v);
}

// ---------------- K4: primary conv 3x3 (256->128) as bf16 MFMA implicit GEMM ---------
// block: 4 waves, 64 oc x 256 px; wave: 64 oc x 64 px (4 rows of 16)
// A-frags (weights) read DIRECTLY from global (L1/L2; coalesced 1KB lines, 4 waves share)
// B (x-halo) double-buffered in LDS via global_load_lds DMA, issued BEFORE compute
__global__ __launch_bounds__(256, 3) void k_primary_mfma(
    const ushort* __restrict__ xbp, const ushort* __restrict__ wtb,
    const float* __restrict__ se_p, const float* __restrict__ be_p,
    const float* __restrict__ ss_p, const float* __restrict__ bs_p,
    const int* __restrict__ slot, ushort* __restrict__ x1b)
{
    int pass = blockIdx.y;
    int sl = slot[pass];
    if (sl < 0) return;
    int s = pass >> 3, b = pass & 7;
    int och = blockIdx.x >> 4;                         // oc half: 0/1
    int tile = blockIdx.x & 15;
    int row0 = (tile >> 2) * 16, col0 = (tile & 3) * 16;

    // x-halo: 18 rows x 4 ks x 18 cols granules = 1296 (+48 pad) of 16B, double-buffered
    __shared__ ushort xlds[2][1344 * 8];               // 2 x 21504 B = 43 KB -> 3 blocks/CU

    int tid = threadIdx.x;
    int wv = tid >> 6, lane = tid & 63;
    int ks = lane >> 4, c = lane & 15;

    const ushort* xb_b = xbp + (size_t)b * 66 * 66 * 256;

    // per-thread staging source offsets (elements), constant across chunks
    int goff[6];
#pragma unroll
    for (int it = 0; it < 5; ++it) {
        int k = it * 256 + tid;
        int r = k / 72, rem = k % 72, ks2 = rem / 18, c2 = rem % 18;
        goff[it] = ((row0 + r) * 66 + (col0 + c2)) * 256 + ks2 * 8;
    }
    {   // tail: 16 real granules (wave 0 writes 64; 48 land in pad, never read)
        int k = 1280 + lane;
        int r = k / 72, rem = k % 72, ks2 = rem / 18, c2 = rem % 18;
        goff[5] = ((row0 + r) * 66 + (col0 + c2)) * 256 + ks2 * 8;
    }
    int lds_us = wv * 512;                             // wave-uniform LDS base (us) per it

    f32x4 acc[4][4];
#pragma unroll
    for (int m = 0; m < 4; ++m)
#pragma unroll
        for (int n = 0; n < 4; ++n) acc[m][n] = (f32x4){0.f, 0.f, 0.f, 0.f};

    const ushort* wslab = wtb + (size_t)(s * 2 + och) * (8 * 18432);
    int Sb = 4 * wv * 72 + ks * 18 + c;                // B-granule base index

    // ---- prologue: stage chunk 0 into buf 0 ----
    {
        const ushort* src = xb_b;                      // cin0 = 0
#pragma unroll
        for (int it = 0; it < 5; ++it)
            gload16(src + goff[it], &xlds[0][(size_t)(it * 2048 + lds_us)]);
        if (wv == 0) gload16(src + goff[5], &xlds[0][1280 * 8]);
    }
    __syncthreads();                                   // vmcnt drain + barrier

    int cur = 0;
    for (int ch = 0; ch < 8; ++ch) {
        // ---- issue next chunk's DMA staging (overlaps with compute below) ----
        if (ch < 7) {
            const ushort* src = xb_b + (ch + 1) * 32;
#pragma unroll
            for (int it = 0; it < 5; ++it)
                gload16(src + goff[it], &xlds[cur ^ 1][(size_t)(it * 2048 + lds_us)]);
            if (wv == 0) gload16(src + goff[5], &xlds[cur ^ 1][1280 * 8]);
        }
        // ---- compute on current buffer: A from global, B from LDS ----
        const ushort* wsrc = wslab + ch * 18432;
        const ushort* xl = &xlds[cur][0];
#pragma unroll
        for (int kh = 0; kh < 3; ++kh) {
#pragma unroll
            for (int kw = 0; kw < 3; ++kw) {
                int tap = kh * 3 + kw;
                bf16x8 afr[4];
#pragma unroll
                for (int m = 0; m < 4; ++m)
                    afr[m] = ld_frag(wsrc + ((size_t)(tap * 64 + m * 16 + c) * 4 + ks) * 8);
#pragma unroll
                for (int n = 0; n < 4; ++n) {
                    bf16x8 bfr = ld_frag(xl + (size_t)(Sb + (n + kh) * 72 + kw) * 8);
#pragma unroll
                    for (int m = 0; m < 4; ++m)
                        acc[m][n] = __builtin_amdgcn_mfma_f32_16x16x32_bf16(
                            afr[m], bfr, acc[m][n], 0, 0, 0);
                }
            }
        }
        __syncthreads();                               // drain staging DMAs + barrier
        cur ^= 1;
    }

    // ---- epilogue: BN + SiLU, bf16 store ----
    const float* scale = (s < 4) ? (se_p + s * ICH) : ss_p;
    const float* shift = (s < 4) ? (be_p + s * ICH) : bs_p;
    ushort* outp = x1b + (size_t)sl * (ICH * NPIX);
    int colg = col0 + c;
#pragma unroll
    for (int m = 0; m < 4; ++m) {
#pragma unroll
        for (int n = 0; n < 4; ++n) {
            int rowg = row0 + 4 * wv + n;
#pragma unroll
            for (int j = 0; j < 4; ++j) {
                int oc = och * 64 + m * 16 + ks * 4 + j;   // D: row=(lane>>4)*4+reg
                float v = acc[m][n][j] * scale[oc] + shift[oc];
                outp[(size_t)oc * NPIX + rowg * 64 + colg] = f2bf(silu_f(v));
            }
        }
    }
}

// ---------------- K5: depthwise 3x3 + BN + SiLU + weighted combine -> out ------------
__global__ __launch_bounds__(256) void k_cheap(
    const ushort* __restrict__ x1b, const float* __restrict__ We_c,
    const float* __restrict__ se_c, const float* __restrict__ be_c,
    const float* __restrict__ Ws_c, const float* __restrict__ ss_c,
    const float* __restrict__ bs_c, const float* __restrict__ wfull,
    const int* __restrict__ slot, float* __restrict__ out)
{
    int blk = blockIdx.x;
    int b = blk >> 7, c = blk & 127;
    __shared__ float img[66][66];
    int tid = threadIdx.x;
    for (int k = tid; k < 66 * 66; k += 256) ((float*)img)[k] = 0.f;
    float o1[16], o2[16];
#pragma unroll
    for (int t = 0; t < 16; ++t) { o1[t] = 0.f; o2[t] = 0.f; }
    __syncthreads();

    for (int s = 0; s < 5; ++s) {
        int sl = slot[s * 8 + b];
        if (sl < 0) continue;
        float wgt = (s < 4) ? wfull[b * 5 + s] : 1.0f;
        const ushort* src = x1b + ((size_t)sl * ICH + c) * NPIX;
        for (int k = tid; k < NPIX / 2; k += 256) {
            int i = k >> 5, jc = (k & 31) * 2;
            unsigned u = *(const unsigned*)(src + i * 64 + jc);
            img[1 + i][1 + jc] = bf2f((unsigned short)(u & 0xFFFFu));
            img[1 + i][2 + jc] = bf2f((unsigned short)(u >> 16));
        }
        float wc[9], sc, sh;
        if (s < 4) {
            const float* wp = We_c + (size_t)(s * ICH + c) * 9;
#pragma unroll
            for (int t = 0; t < 9; ++t) wc[t] = wp[t];
            sc = se_c[s * ICH + c]; sh = be_c[s * ICH + c];
        } else {
            const float* wp = Ws_c + (size_t)c * 9;
#pragma unroll
            for (int t = 0; t < 9; ++t) wc[t] = wp[t];
            sc = ss_c[c]; sh = bs_c[c];
        }
        __syncthreads();
#pragma unroll
        for (int t = 0; t < 16; ++t) {
            int p = tid + t * 256;
            int i = p >> 6, j = p & 63;
            float center = img[1 + i][1 + j];
            float d = 0.f;
#pragma unroll
            for (int kh = 0; kh < 3; ++kh)
#pragma unroll
                for (int kw = 0; kw < 3; ++kw)
                    d = fmaf(wc[kh * 3 + kw], img[i + kh][j + kw], d);
            float v = d * sc + sh;
            o1[t] += wgt * center;
            o2[t] += wgt * silu_f(v);
        }
        __syncthreads();
    }

    float* out1 = out + ((size_t)(b * 256) + c) * NPIX;
    float* out2 = out + ((size_t)(b * 256) + 128 + c) * NPIX;
#pragma unroll
    for (int t = 0; t < 16; ++t) {
        int p = tid + t * 256;
        out1[p] = o1[t];
        out2[p] = o2[t];
    }
}

// ---------------- launcher ----------------
extern "C" void kernel_launch(void* const* d_in, const int* in_sizes, int n_in,
                              void* d_out, int out_size, void* d_ws, size_t ws_size,
                              hipStream_t stream)
{
    const float* x    = (const float*)d_in[0];
    const float* Wr1  = (const float*)d_in[1];
    const float* sr1  = (const float*)d_in[2];
    const float* br1  = (const float*)d_in[3];
    const float* Wr2  = (const float*)d_in[4];
    const float* sr2  = (const float*)d_in[5];
    const float* br2  = (const float*)d_in[6];
    const float* We_p = (const float*)d_in[7];
    const float* se_p = (const float*)d_in[8];
    const float* be_p = (const float*)d_in[9];
    const float* We_c = (const float*)d_in[10];
    const float* se_c = (const float*)d_in[11];
    const float* be_c = (const float*)d_in[12];
    const float* Ws_p = (const float*)d_in[13];
    const float* ss_p = (const float*)d_in[14];
    const float* bs_p = (const float*)d_in[15];
    const float* Ws_c = (const float*)d_in[16];
    const float* ss_c = (const float*)d_in[17];
    const float* bs_c = (const float*)d_in[18];
    const int*  topk  = (const int*)d_in[19];
    float* out = (float*)d_out;
    float* ws  = (float*)d_ws;

    float*  xd    = ws + OFF_XD;
    float*  hmean = ws + OFF_HMEAN;
    float*  wfull = ws + OFF_WFULL;
    int*    slot  = (int*)(ws + OFF_SLOT);
    ushort* wtb   = (ushort*)(ws + OFF_WTB);
    ushort* xbp   = (ushort*)(ws + OFF_XBP);
    ushort* x1b   = (ushort*)(ws + OFF_X1B);
    // requires ws_size >= 48.1 MB (round 3 proved >= 58.3 MB works)

    // zero padded-x borders (async, graph-capturable), then fill interior
    hipMemsetAsync(xbp, 0, (size_t)8 * 66 * 66 * 256 * sizeof(ushort), stream);
    k_avgpool<<<512, 256, 0, stream>>>(x, xd);
    k_xprep<<<512, 256, 0, stream>>>(x, xbp);
    k_wprep16<<<5760, 256, 0, stream>>>(We_p, Ws_p, wtb);
    k_router_conv<<<256, 256, 0, stream>>>(xd, Wr1, sr1, br1, hmean);
    k_router_final<<<1, 64, 0, stream>>>(hmean, Wr2, sr2, br2, topk, wfull, slot);
    k_primary_mfma<<<dim3(32, 40), 256, 0, stream>>>(xbp, wtb, se_p, be_p, ss_p, bs_p, slot, x1b);
    k_cheap<<<1024, 256, 0, stream>>>(x1b, We_c, se_c, be_c, Ws_c, ss_c, bs_c, wfull, slot, out);
}

// Round 7
// 301.894 us; speedup vs baseline: 1.2089x; 1.2089x over previous
//
#include <hip/hip_runtime.h>
#include <hip/hip_bf16.h>

// ---------------- problem constants ----------------
constexpr int BATCH = 8;
constexpr int CIN   = 256;
constexpr int HH    = 64;
constexpr int WW    = 64;
constexpr int NPIX  = HH * WW;        // 4096
constexpr int ICH   = 128;            // init_ch == new_ch

// ---------------- workspace layout (in floats) ----------------
constexpr size_t OFF_XD    = 0;                        // 8*256*16*16 = 524288 f
constexpr size_t OFF_HMEAN = 524288;                   // 256 f
constexpr size_t OFF_WFULL = 524544;                   // 64 f
constexpr size_t OFF_SLOT  = 524608;                   // 64 f (ints)
constexpr size_t OFF_WTB   = 524672;                   // bf16 weights: 1,474,560 us = 737,280 f
constexpr size_t OFF_XBP   = OFF_WTB + 737280;         // bf16 x padded NHWC 8*66*66*256 us = 4,460,544 f
constexpr size_t OFF_X1B   = OFF_XBP + 4460544;        // bf16 x1: 12,582,912 us = 6,291,456 f
// total = 12,013,952 floats = 48.1 MB of d_ws (round-3 proved >= 58.3 MB available)

typedef __bf16  bf16x8 __attribute__((ext_vector_type(8)));
typedef float   f32x4  __attribute__((ext_vector_type(4)));

__device__ __forceinline__ float silu_f(float v) { return v / (1.f + __expf(-v)); }

__device__ __forceinline__ unsigned short f2bf(float f) {
    return __builtin_bit_cast(unsigned short, __float2bfloat16(f));
}
__device__ __forceinline__ float bf2f(unsigned short u) {
    return __builtin_bit_cast(float, (unsigned)u << 16);
}
__device__ __forceinline__ bf16x8 ld_frag(const ushort* p) {
    uint4 v = *(const uint4*)p;          // ds_read_b128
    return __builtin_bit_cast(bf16x8, v);
}
// async global->LDS DMA, 16B per lane; LDS dest = wave-uniform base + lane*16
__device__ __forceinline__ void gload16(const ushort* g, ushort* l) {
    __builtin_amdgcn_global_load_lds(
        (const __attribute__((address_space(1))) void*)g,
        (__attribute__((address_space(3))) void*)l, 16, 0, 0);
}

// ---------------- K1: 4x4 avg pool  x[8,256,64,64] -> xd[8,256,16,16] ----------------
__global__ void k_avgpool(const float* __restrict__ x, float* __restrict__ xd)
{
    int t = blockIdx.x * 256 + threadIdx.x;
    int jb = t & 3, i = (t >> 2) & 15, c = (t >> 6) & 255, b = t >> 14;
    const float* src = x + ((size_t)(b * CIN + c) * HH + i * 4) * WW + jb * 16;
    float s0 = 0.f, s1 = 0.f, s2 = 0.f, s3 = 0.f;
#pragma unroll
    for (int r = 0; r < 4; ++r) {
        const float4* p = (const float4*)(src + r * WW);
        float4 a = p[0], b4 = p[1], c4 = p[2], d4 = p[3];
        s0 += a.x + a.y + a.z + a.w;
        s1 += b4.x + b4.y + b4.z + b4.w;
        s2 += c4.x + c4.y + c4.z + c4.w;
        s3 += d4.x + d4.y + d4.z + d4.w;
    }
    float4 o;
    o.x = s0 * 0.0625f; o.y = s1 * 0.0625f; o.z = s2 * 0.0625f; o.w = s3 * 0.0625f;
    *(float4*)(xd + ((size_t)(b * CIN + c) * 16 + i) * 16 + jb * 4) = o;
}

// ---------------- K1b: x fp32 NCHW -> bf16 padded NHWC [b][row+1][col+1][cin] --------
__global__ __launch_bounds__(256) void k_xprep(const float* __restrict__ x,
                                               ushort* __restrict__ xbp)
{
    int b = blockIdx.x >> 6, row = blockIdx.x & 63;
    __shared__ ushort tile[64 * 258];    // [col][cin], pad 2 to break bank conflicts
    int tid = threadIdx.x;
    const float* src = x + ((size_t)b * CIN * HH + row) * WW;   // + cin*4096 + col
    for (int k = tid; k < 256 * 64; k += 256) {
        int cin = k >> 6, col = k & 63;                         // coalesced fp32 read
        tile[col * 258 + cin] = f2bf(src[(size_t)cin * NPIX + col]);
    }
    __syncthreads();
    ushort* dst = xbp + ((size_t)(b * 66 + row + 1) * 66 + 1) * 256;
    for (int k = tid; k < 64 * 128; k += 256) {
        int col = k >> 7, cp = (k & 127) * 2;
        unsigned u0 = tile[col * 258 + cp];
        unsigned u1 = tile[col * 258 + cp + 1];
        *(unsigned*)(dst + (size_t)col * 256 + cp) = u0 | (u1 << 16);  // coalesced
    }
}

// ---------------- K2: router conv3x3 (256->32) + BN + SiLU, mean over HW -------------
__global__ __launch_bounds__(256) void k_router_conv(
    const float* __restrict__ xd, const float* __restrict__ Wr1,
    const float* __restrict__ sr1, const float* __restrict__ br1,
    float* __restrict__ hmean)
{
    int b = blockIdx.x >> 5, r = blockIdx.x & 31;
    __shared__ float wl[9 * 256];
    __shared__ float red[256];
    int tid = threadIdx.x;
    for (int k = tid; k < 2304; k += 256) {
        int cin = k / 9, tap = k % 9;
        wl[tap * 256 + cin] = Wr1[r * 2304 + k];
    }
    __syncthreads();
    const float* xb = xd + (size_t)b * CIN * 256;
    int i = tid >> 4, j = tid & 15;
    float acc = 0.f;
#pragma unroll
    for (int kh = 0; kh < 3; ++kh) {
        int ii = i + kh - 1;
        bool oki = (unsigned)ii < 16u;
        int iis = oki ? ii : 0;
#pragma unroll
        for (int kw = 0; kw < 3; ++kw) {
            int jj = j + kw - 1;
            bool ok = oki && ((unsigned)jj < 16u);
            int off = iis * 16 + (((unsigned)jj < 16u) ? jj : 0);
            const float* wt = wl + (kh * 3 + kw) * 256;
            float t = 0.f;
#pragma unroll 8
            for (int cin = 0; cin < 256; ++cin)
                t = fmaf(wt[cin], xb[cin * 256 + off], t);
            if (ok) acc += t;
        }
    }
    float h = silu_f(acc * sr1[r] + br1[r]);
    red[tid] = h;
    __syncthreads();
    for (int st = 128; st > 0; st >>= 1) {
        if (tid < st) red[tid] += red[tid + st];
        __syncthreads();
    }
    if (tid == 0) hmean[b * 32 + r] = red[0] * (1.f / 256.f);
}

// ---------------- K3: router head: 1x1 conv + BN, softmax, top-k, slot compaction ----
__global__ void k_router_final(const float* __restrict__ hmean,
                               const float* __restrict__ Wr2, const float* __restrict__ sr2,
                               const float* __restrict__ br2, const int* __restrict__ topk_p,
                               float* __restrict__ wfull, int* __restrict__ slot)
{
    __shared__ float lg[8][4];
    __shared__ float wf[8][5];
    int tid = threadIdx.x;
    if (tid < 32) {
        int b = tid >> 2, e = tid & 3;
        float a = 0.f;
        for (int r = 0; r < 32; ++r) a += Wr2[e * 32 + r] * hmean[b * 32 + r];
        lg[b][e] = a * sr2[e] + br2[e];
    }
    __syncthreads();
    if (tid < 8) {
        int b = tid;
        float l0 = lg[b][0], l1 = lg[b][1], l2 = lg[b][2], l3 = lg[b][3];
        float mx = fmaxf(fmaxf(l0, l1), fmaxf(l2, l3));
        float e0 = __expf(l0 - mx), e1 = __expf(l1 - mx), e2 = __expf(l2 - mx), e3 = __expf(l3 - mx);
        float sum = e0 + e1 + e2 + e3;
        float w[4] = { e0 / sum, e1 / sum, e2 / sum, e3 / sum };
        int k = topk_p[0];
        if (k > 4) k = 4;
        bool taken[4] = { false, false, false, false };
        float tv[4]; int ti[4]; float tsum = 0.f;
        for (int t = 0; t < k; ++t) {
            float best = -1e30f; int bi = 0;
            for (int e = 0; e < 4; ++e)
                if (!taken[e] && w[e] > best) { best = w[e]; bi = e; }
            taken[bi] = true; tv[t] = best; ti[t] = bi; tsum += best;
        }
        float inv = 1.f / (tsum + 1e-6f);
        float o[4] = { 0.f, 0.f, 0.f, 0.f };
        for (int t = 0; t < k; ++t) o[ti[t]] = tv[t] * inv;
        for (int e = 0; e < 4; ++e) { wf[b][e] = o[e]; wfull[b * 5 + e] = o[e]; }
        wf[b][4] = 1.f; wfull[b * 5 + 4] = 1.f;
    }
    __syncthreads();
    if (tid == 0) {
        int cnt = 0;
        for (int s = 0; s < 5; ++s)
            for (int b = 0; b < 8; ++b)
                slot[s * 8 + b] = (wf[b][s] != 0.f) ? (cnt++) : -1;
    }
}

// ---------------- Kprep: weights fp32 OIHW -> bf16 [s][half][chunk][tap][oc64][ks][8] -
__global__ void k_wprep16(const float* __restrict__ We_p, const float* __restrict__ Ws_p,
                          ushort* __restrict__ wtb)
{
    int t = blockIdx.x * 256 + threadIdx.x;   // 1,474,560 dest-linear
    int k5  = t & 31;                          // ks*8+j = cin-in-chunk
    int oc  = (t >> 5) & 63;
    int tap = (t >> 11) % 9;
    int blk = t / 18432;                       // s*16 + h*8 + chunk
    int chunk = blk & 7;
    int h     = (blk >> 3) & 1;
    int s     = blk >> 4;
    int cin   = chunk * 32 + k5;
    int ocg   = h * 64 + oc;
    float v = (s < 4) ? We_p[((size_t)(s * 128 + ocg) * 256 + cin) * 9 + tap]
                      : Ws_p[((size_t)ocg * 256 + cin) * 9 + tap];
    wtb[t] = f2bf(v);
}

// ---------------- K4: primary conv 3x3 (256->128) as bf16 MFMA implicit GEMM ---------
// block: 4 waves, 64 oc x 256 px; wave: 64 oc x 64 px (4 rows of 16)
// BOTH operands double-buffered in LDS (114 KB), staged via global_load_lds DMA
// issued BEFORE the compute phase (T3-minimum pipeline); 1 block/CU
__global__ __launch_bounds__(256, 1) void k_primary_mfma(
    const ushort* __restrict__ xbp, const ushort* __restrict__ wtb,
    const float* __restrict__ se_p, const float* __restrict__ be_p,
    const float* __restrict__ ss_p, const float* __restrict__ bs_p,
    const int* __restrict__ slot, ushort* __restrict__ x1b)
{
    int pass = blockIdx.y;
    int sl = slot[pass];
    if (sl < 0) return;
    int s = pass >> 3, b = pass & 7;
    int och = blockIdx.x >> 4;                         // oc half: 0/1
    int tile = blockIdx.x & 15;
    int row0 = (tile >> 2) * 16, col0 = (tile & 3) * 16;

    __shared__ ushort wlds[2][2304 * 8];               // 2 x 36864 B (weights [tap][oc][ks])
    __shared__ ushort xlds[2][1344 * 8];               // 2 x 21504 B (x halo [row][ks][col])

    int tid = threadIdx.x;
    int wv = tid >> 6, lane = tid & 63;
    int ks = lane >> 4, c = lane & 15;

    const ushort* xb_b = xbp + (size_t)b * 66 * 66 * 256;
    const ushort* wslab = wtb + (size_t)(s * 2 + och) * (8 * 18432);

    // per-thread x staging source offsets (elements), constant across chunks
    int goff[6];
#pragma unroll
    for (int it = 0; it < 5; ++it) {
        int k = it * 256 + tid;
        int r = k / 72, rem = k % 72, ks2 = rem / 18, c2 = rem % 18;
        goff[it] = ((row0 + r) * 66 + (col0 + c2)) * 256 + ks2 * 8;
    }
    {   // tail: granules 1280..1295 real; 1296..1343 pad (written, never read)
        int k = 1280 + lane;
        int r = k / 72, rem = k % 72, ks2 = rem / 18, c2 = rem % 18;
        goff[5] = ((row0 + r) * 66 + (col0 + c2)) * 256 + ks2 * 8;
    }
    int lds_us = wv * 512;                             // (wave-uniform base)/us per it

    f32x4 acc[4][4];
#pragma unroll
    for (int m = 0; m < 4; ++m)
#pragma unroll
        for (int n = 0; n < 4; ++n) acc[m][n] = (f32x4){0.f, 0.f, 0.f, 0.f};

    int Sb = 4 * wv * 72 + ks * 18 + c;                // B-granule base index

    auto stage = [&](int ch, int buf) {
        // weights: 2304 granules, linear both sides
        const ushort* wsrc = wslab + ch * 18432;
#pragma unroll
        for (int it = 0; it < 9; ++it)
            gload16(wsrc + (size_t)(it * 256 + tid) * 8,
                    &wlds[buf][(size_t)(it * 2048 + lds_us)]);
        // x halo: 1296 granules (+ pad), pre-padded source -> no bounds branches
        const ushort* xsrc = xb_b + ch * 32;
#pragma unroll
        for (int it = 0; it < 5; ++it)
            gload16(xsrc + goff[it], &xlds[buf][(size_t)(it * 2048 + lds_us)]);
        if (wv == 0) gload16(xsrc + goff[5], &xlds[buf][1280 * 8]);
    };

    stage(0, 0);
    __syncthreads();                                   // vmcnt(0) drain + barrier

    int cur = 0;
    for (int ch = 0; ch < 8; ++ch) {
        if (ch < 7) stage(ch + 1, cur ^ 1);            // issue DMA BEFORE compute
        const ushort* wl = &wlds[cur][0];
        const ushort* xl = &xlds[cur][0];
#pragma unroll
        for (int kh = 0; kh < 3; ++kh) {
#pragma unroll
            for (int kw = 0; kw < 3; ++kw) {
                int tap = kh * 3 + kw;
                bf16x8 afr[4];
#pragma unroll
                for (int m = 0; m < 4; ++m)
                    afr[m] = ld_frag(wl + ((size_t)(tap * 64 + m * 16 + c) * 4 + ks) * 8);
#pragma unroll
                for (int n = 0; n < 4; ++n) {
                    bf16x8 bfr = ld_frag(xl + (size_t)(Sb + (n + kh) * 72 + kw) * 8);
#pragma unroll
                    for (int m = 0; m < 4; ++m)
                        acc[m][n] = __builtin_amdgcn_mfma_f32_16x16x32_bf16(
                            afr[m], bfr, acc[m][n], 0, 0, 0);
                }
            }
        }
        __syncthreads();                               // drains next-chunk DMAs too
        cur ^= 1;
    }

    // ---- epilogue: BN + SiLU, bf16 store ----
    const float* scale = (s < 4) ? (se_p + s * ICH) : ss_p;
    const float* shift = (s < 4) ? (be_p + s * ICH) : bs_p;
    ushort* outp = x1b + (size_t)sl * (ICH * NPIX);
    int colg = col0 + c;
#pragma unroll
    for (int m = 0; m < 4; ++m) {
#pragma unroll
        for (int n = 0; n < 4; ++n) {
            int rowg = row0 + 4 * wv + n;
#pragma unroll
            for (int j = 0; j < 4; ++j) {
                int oc = och * 64 + m * 16 + ks * 4 + j;   // D: row=(lane>>4)*4+reg
                float v = acc[m][n][j] * scale[oc] + shift[oc];
                outp[(size_t)oc * NPIX + rowg * 64 + colg] = f2bf(silu_f(v));
            }
        }
    }
}

// ---------------- K5: depthwise 3x3 + BN + SiLU + weighted combine -> out ------------
// block (b,c): stages all (<=3) active slots into parallel LDS buffers, 2 barriers
__global__ __launch_bounds__(256) void k_cheap(
    const ushort* __restrict__ x1b, const float* __restrict__ We_c,
    const float* __restrict__ se_c, const float* __restrict__ be_c,
    const float* __restrict__ Ws_c, const float* __restrict__ ss_c,
    const float* __restrict__ bs_c, const float* __restrict__ wfull,
    const int* __restrict__ slot, float* __restrict__ out)
{
    int blk = blockIdx.x;
    int b = blk >> 7, c = blk & 127;
    __shared__ float img[3][66][66];                   // 52.3 KB -> 3 blocks/CU
    int tid = threadIdx.x;

    // gather active slots (block-uniform; <= 3 = top_k + shared)
    int nact = 0;
    int sls[3], sidx[3];
    float wgts[3];
    for (int s = 0; s < 5; ++s) {
        int sl = slot[s * 8 + b];
        if (sl < 0) continue;
        sls[nact] = sl; sidx[nact] = s;
        wgts[nact] = (s < 4) ? wfull[b * 5 + s] : 1.0f;
        ++nact;
    }

    for (int k = tid; k < 3 * 66 * 66; k += 256) ((float*)img)[k] = 0.f;
    __syncthreads();

#pragma unroll
    for (int a = 0; a < 3; ++a) {
        if (a < nact) {
            const ushort* src = x1b + ((size_t)sls[a] * ICH + c) * NPIX;
            for (int k = tid; k < 1024; k += 256) {
                int i = k >> 4, jc = (k & 15) * 4;
                uint2 u = *(const uint2*)(src + i * 64 + jc);
                img[a][1 + i][1 + jc] = bf2f((unsigned short)(u.x & 0xFFFFu));
                img[a][1 + i][2 + jc] = bf2f((unsigned short)(u.x >> 16));
                img[a][1 + i][3 + jc] = bf2f((unsigned short)(u.y & 0xFFFFu));
                img[a][1 + i][4 + jc] = bf2f((unsigned short)(u.y >> 16));
            }
        }
    }
    __syncthreads();

    float o1[16], o2[16];
#pragma unroll
    for (int t = 0; t < 16; ++t) { o1[t] = 0.f; o2[t] = 0.f; }

#pragma unroll
    for (int a = 0; a < 3; ++a) {
        if (a < nact) {
            int s = sidx[a];
            const float* wp = (s < 4) ? (We_c + (size_t)(s * ICH + c) * 9)
                                      : (Ws_c + (size_t)c * 9);
            float wc0 = wp[0], wc1 = wp[1], wc2 = wp[2], wc3 = wp[3], wc4 = wp[4],
                  wc5 = wp[5], wc6 = wp[6], wc7 = wp[7], wc8 = wp[8];
            float sc = (s < 4) ? se_c[s * ICH + c] : ss_c[c];
            float sh = (s < 4) ? be_c[s * ICH + c] : bs_c[c];
            float wgt = wgts[a];
#pragma unroll
            for (int t = 0; t < 16; ++t) {
                int p = tid + t * 256;
                int i = p >> 6, j = p & 63;
                float center = img[a][1 + i][1 + j];
                float d = wc0 * img[a][i][j];
                d = fmaf(wc1, img[a][i][j + 1], d);
                d = fmaf(wc2, img[a][i][j + 2], d);
                d = fmaf(wc3, img[a][i + 1][j], d);
                d = fmaf(wc4, center, d);
                d = fmaf(wc5, img[a][i + 1][j + 2], d);
                d = fmaf(wc6, img[a][i + 2][j], d);
                d = fmaf(wc7, img[a][i + 2][j + 1], d);
                d = fmaf(wc8, img[a][i + 2][j + 2], d);
                float v = d * sc + sh;
                o1[t] += wgt * center;
                o2[t] += wgt * silu_f(v);
            }
        }
    }

    float* out1 = out + ((size_t)(b * 256) + c) * NPIX;
    float* out2 = out + ((size_t)(b * 256) + 128 + c) * NPIX;
#pragma unroll
    for (int t = 0; t < 16; ++t) {
        int p = tid + t * 256;
        out1[p] = o1[t];
        out2[p] = o2[t];
    }
}

// ---------------- launcher ----------------
extern "C" void kernel_launch(void* const* d_in, const int* in_sizes, int n_in,
                              void* d_out, int out_size, void* d_ws, size_t ws_size,
                              hipStream_t stream)
{
    const float* x    = (const float*)d_in[0];
    const float* Wr1  = (const float*)d_in[1];
    const float* sr1  = (const float*)d_in[2];
    const float* br1  = (const float*)d_in[3];
    const float* Wr2  = (const float*)d_in[4];
    const float* sr2  = (const float*)d_in[5];
    const float* br2  = (const float*)d_in[6];
    const float* We_p = (const float*)d_in[7];
    const float* se_p = (const float*)d_in[8];
    const float* be_p = (const float*)d_in[9];
    const float* We_c = (const float*)d_in[10];
    const float* se_c = (const float*)d_in[11];
    const float* be_c = (const float*)d_in[12];
    const float* Ws_p = (const float*)d_in[13];
    const float* ss_p = (const float*)d_in[14];
    const float* bs_p = (const float*)d_in[15];
    const float* Ws_c = (const float*)d_in[16];
    const float* ss_c = (const float*)d_in[17];
    const float* bs_c = (const float*)d_in[18];
    const int*  topk  = (const int*)d_in[19];
    float* out = (float*)d_out;
    float* ws  = (float*)d_ws;

    float*  xd    = ws + OFF_XD;
    float*  hmean = ws + OFF_HMEAN;
    float*  wfull = ws + OFF_WFULL;
    int*    slot  = (int*)(ws + OFF_SLOT);
    ushort* wtb   = (ushort*)(ws + OFF_WTB);
    ushort* xbp   = (ushort*)(ws + OFF_XBP);
    ushort* x1b   = (ushort*)(ws + OFF_X1B);
    // requires ws_size >= 48.1 MB (round 3 proved >= 58.3 MB works)

    hipMemsetAsync(xbp, 0, (size_t)8 * 66 * 66 * 256 * sizeof(ushort), stream);
    k_avgpool<<<512, 256, 0, stream>>>(x, xd);
    k_xprep<<<512, 256, 0, stream>>>(x, xbp);
    k_wprep16<<<5760, 256, 0, stream>>>(We_p, Ws_p, wtb);
    k_router_conv<<<256, 256, 0, stream>>>(xd, Wr1, sr1, br1, hmean);
    k_router_final<<<1, 64, 0, stream>>>(hmean, Wr2, sr2, br2, topk, wfull, slot);
    k_primary_mfma<<<dim3(32, 40), 256, 0, stream>>>(xbp, wtb, se_p, be_p, ss_p, bs_p, slot, x1b);
    k_cheap<<<1024, 256, 0, stream>>>(x1b, We_c, se_c, be_c, Ws_c, ss_c, bs_c, wfull, slot, out);
}

// Round 9
// 300.945 us; speedup vs baseline: 1.2127x; 1.0032x over previous
//
#include <hip/hip_runtime.h>
#include <hip/hip_bf16.h>

// ---------------- problem constants ----------------
constexpr int BATCH = 8;
constexpr int CIN   = 256;
constexpr int HH    = 64;
constexpr int WW    = 64;
constexpr int NPIX  = HH * WW;        // 4096
constexpr int ICH   = 128;            // init_ch == new_ch

// ---------------- workspace layout (in floats) ----------------
constexpr size_t OFF_XD    = 0;                        // 8*256*16*16 = 524288 f
constexpr size_t OFF_HMEAN = 524288;                   // 256 f
constexpr size_t OFF_WFULL = 524544;                   // 64 f
constexpr size_t OFF_SLOT  = 524608;                   // 64 f (ints)
constexpr size_t OFF_WTB   = 524672;                   // bf16 weights: 1,474,560 us = 737,280 f
constexpr size_t OFF_XBP   = OFF_WTB + 737280;         // bf16 x padded NHWC 8*66*66*256 us = 4,460,544 f
constexpr size_t OFF_X1B   = OFF_XBP + 4460544;        // bf16 x1: 12,582,912 us = 6,291,456 f
// total = 12,013,952 floats = 48.1 MB of d_ws

typedef __bf16  bf16x8 __attribute__((ext_vector_type(8)));
typedef float   f32x4  __attribute__((ext_vector_type(4)));

__device__ __forceinline__ float silu_f(float v) { return v / (1.f + __expf(-v)); }

__device__ __forceinline__ unsigned short f2bf(float f) {
    return __builtin_bit_cast(unsigned short, __float2bfloat16(f));
}
__device__ __forceinline__ float bf2f(unsigned short u) {
    return __builtin_bit_cast(float, (unsigned)u << 16);
}
__device__ __forceinline__ bf16x8 ld_frag(const ushort* p) {
    uint4 v = *(const uint4*)p;          // ds_read_b128
    return __builtin_bit_cast(bf16x8, v);
}
// async global->LDS DMA, 16B per lane; LDS dest = wave-uniform base + lane*16
__device__ __forceinline__ void gload16(const ushort* g, ushort* l) {
    __builtin_amdgcn_global_load_lds(
        (const __attribute__((address_space(1))) void*)g,
        (__attribute__((address_space(3))) void*)l, 16, 0, 0);
}

// ---------------- K1: 4x4 avg pool  x[8,256,64,64] -> xd[8,256,16,16] ----------------
__global__ void k_avgpool(const float* __restrict__ x, float* __restrict__ xd)
{
    int t = blockIdx.x * 256 + threadIdx.x;
    int jb = t & 3, i = (t >> 2) & 15, c = (t >> 6) & 255, b = t >> 14;
    const float* src = x + ((size_t)(b * CIN + c) * HH + i * 4) * WW + jb * 16;
    float s0 = 0.f, s1 = 0.f, s2 = 0.f, s3 = 0.f;
#pragma unroll
    for (int r = 0; r < 4; ++r) {
        const float4* p = (const float4*)(src + r * WW);
        float4 a = p[0], b4 = p[1], c4 = p[2], d4 = p[3];
        s0 += a.x + a.y + a.z + a.w;
        s1 += b4.x + b4.y + b4.z + b4.w;
        s2 += c4.x + c4.y + c4.z + c4.w;
        s3 += d4.x + d4.y + d4.z + d4.w;
    }
    float4 o;
    o.x = s0 * 0.0625f; o.y = s1 * 0.0625f; o.z = s2 * 0.0625f; o.w = s3 * 0.0625f;
    *(float4*)(xd + ((size_t)(b * CIN + c) * 16 + i) * 16 + jb * 4) = o;
}

// ---------------- K1b: x fp32 NCHW -> bf16 padded NHWC [b][row+1][col+1][cin] --------
__global__ __launch_bounds__(256) void k_xprep(const float* __restrict__ x,
                                               ushort* __restrict__ xbp)
{
    int b = blockIdx.x >> 6, row = blockIdx.x & 63;
    __shared__ ushort tile[64 * 258];    // [col][cin], pad 2 to break bank conflicts
    int tid = threadIdx.x;
    const float* src = x + ((size_t)b * CIN * HH + row) * WW;   // + cin*4096 + col
    for (int k = tid; k < 256 * 64; k += 256) {
        int cin = k >> 6, col = k & 63;                         // coalesced fp32 read
        tile[col * 258 + cin] = f2bf(src[(size_t)cin * NPIX + col]);
    }
    __syncthreads();
    ushort* dst = xbp + ((size_t)(b * 66 + row + 1) * 66 + 1) * 256;
    for (int k = tid; k < 64 * 128; k += 256) {
        int col = k >> 7, cp = (k & 127) * 2;
        unsigned u0 = tile[col * 258 + cp];
        unsigned u1 = tile[col * 258 + cp + 1];
        *(unsigned*)(dst + (size_t)col * 256 + cp) = u0 | (u1 << 16);  // coalesced
    }
}

// ---------------- K2: router conv3x3 (256->32) + BN + SiLU, mean over HW -------------
__global__ __launch_bounds__(256) void k_router_conv(
    const float* __restrict__ xd, const float* __restrict__ Wr1,
    const float* __restrict__ sr1, const float* __restrict__ br1,
    float* __restrict__ hmean)
{
    int b = blockIdx.x >> 5, r = blockIdx.x & 31;
    __shared__ float wl[9 * 256];
    __shared__ float red[256];
    int tid = threadIdx.x;
    for (int k = tid; k < 2304; k += 256) {
        int cin = k / 9, tap = k % 9;
        wl[tap * 256 + cin] = Wr1[r * 2304 + k];
    }
    __syncthreads();
    const float* xb = xd + (size_t)b * CIN * 256;
    int i = tid >> 4, j = tid & 15;
    float acc = 0.f;
#pragma unroll
    for (int kh = 0; kh < 3; ++kh) {
        int ii = i + kh - 1;
        bool oki = (unsigned)ii < 16u;
        int iis = oki ? ii : 0;
#pragma unroll
        for (int kw = 0; kw < 3; ++kw) {
            int jj = j + kw - 1;
            bool ok = oki && ((unsigned)jj < 16u);
            int off = iis * 16 + (((unsigned)jj < 16u) ? jj : 0);
            const float* wt = wl + (kh * 3 + kw) * 256;
            float t = 0.f;
#pragma unroll 8
            for (int cin = 0; cin < 256; ++cin)
                t = fmaf(wt[cin], xb[cin * 256 + off], t);
            if (ok) acc += t;
        }
    }
    float h = silu_f(acc * sr1[r] + br1[r]);
    red[tid] = h;
    __syncthreads();
    for (int st = 128; st > 0; st >>= 1) {
        if (tid < st) red[tid] += red[tid + st];
        __syncthreads();
    }
    if (tid == 0) hmean[b * 32 + r] = red[0] * (1.f / 256.f);
}

// ---------------- K3: router head: 1x1 conv + BN, softmax, top-k, slot compaction ----
__global__ void k_router_final(const float* __restrict__ hmean,
                               const float* __restrict__ Wr2, const float* __restrict__ sr2,
                               const float* __restrict__ br2, const int* __restrict__ topk_p,
                               float* __restrict__ wfull, int* __restrict__ slot)
{
    __shared__ float lg[8][4];
    __shared__ float wf[8][5];
    int tid = threadIdx.x;
    if (tid < 32) {
        int b = tid >> 2, e = tid & 3;
        float a = 0.f;
        for (int r = 0; r < 32; ++r) a += Wr2[e * 32 + r] * hmean[b * 32 + r];
        lg[b][e] = a * sr2[e] + br2[e];
    }
    __syncthreads();
    if (tid < 8) {
        int b = tid;
        float l0 = lg[b][0], l1 = lg[b][1], l2 = lg[b][2], l3 = lg[b][3];
        float mx = fmaxf(fmaxf(l0, l1), fmaxf(l2, l3));
        float e0 = __expf(l0 - mx), e1 = __expf(l1 - mx), e2 = __expf(l2 - mx), e3 = __expf(l3 - mx);
        float sum = e0 + e1 + e2 + e3;
        float w[4] = { e0 / sum, e1 / sum, e2 / sum, e3 / sum };
        int k = topk_p[0];
        if (k > 4) k = 4;
        bool taken[4] = { false, false, false, false };
        float tv[4]; int ti[4]; float tsum = 0.f;
        for (int t = 0; t < k; ++t) {
            float best = -1e30f; int bi = 0;
            for (int e = 0; e < 4; ++e)
                if (!taken[e] && w[e] > best) { best = w[e]; bi = e; }
            taken[bi] = true; tv[t] = best; ti[t] = bi; tsum += best;
        }
        float inv = 1.f / (tsum + 1e-6f);
        float o[4] = { 0.f, 0.f, 0.f, 0.f };
        for (int t = 0; t < k; ++t) o[ti[t]] = tv[t] * inv;
        for (int e = 0; e < 4; ++e) { wf[b][e] = o[e]; wfull[b * 5 + e] = o[e]; }
        wf[b][4] = 1.f; wfull[b * 5 + 4] = 1.f;
    }
    __syncthreads();
    if (tid == 0) {
        int cnt = 0;
        for (int s = 0; s < 5; ++s)
            for (int b = 0; b < 8; ++b)
                slot[s * 8 + b] = (wf[b][s] != 0.f) ? (cnt++) : -1;
    }
}

// ---------------- Kprep: weights fp32 OIHW -> bf16 [s][half][chunk][tap][ks][oc][8] --
// A layout [tap][ks][oc]: quarter-wave reads contiguous 256B (2 lanes/bank = free)
__global__ void k_wprep16(const float* __restrict__ We_p, const float* __restrict__ Ws_p,
                          ushort* __restrict__ wtb)
{
    int t = blockIdx.x * 256 + threadIdx.x;   // 1,474,560 dest-linear
    int j   = t & 7;                           // cin-in-granule
    int oc  = (t >> 3) & 63;
    int ks  = (t >> 9) & 3;
    int tap = (t >> 11) % 9;
    int blk = t / 18432;                       // s*16 + h*8 + chunk
    int chunk = blk & 7;
    int h     = (blk >> 3) & 1;
    int s     = blk >> 4;
    int cin   = chunk * 32 + ks * 8 + j;
    int ocg   = h * 64 + oc;
    float v = (s < 4) ? We_p[((size_t)(s * 128 + ocg) * 256 + cin) * 9 + tap]
                      : Ws_p[((size_t)ocg * 256 + cin) * 9 + tap];
    wtb[t] = f2bf(v);
}

// ---------------- K4: primary conv 3x3 (256->128) as bf16 MFMA implicit GEMM ---------
// block: 4 waves, 64 oc x 256 px; wave: 64 oc x 64 px (4 rows of 16)
// LDS: w double-buffered (2x36.9KB, [tap][ks][oc]); x TRIPLE-buffered (3x24KB)
// T4 counted-vmcnt pipeline: per chunk issue w(i+1), x(i+2); wait vmcnt(6) -> only
// loads with a full chunk of compute cover are drained; raw s_barrier fenced by
// sched_barrier(0) on BOTH sides (rule #18: no ds_read may cross the barrier)
__global__ __launch_bounds__(256, 1) void k_primary_mfma(
    const ushort* __restrict__ xbp, const ushort* __restrict__ wtb,
    const float* __restrict__ se_p, const float* __restrict__ be_p,
    const float* __restrict__ ss_p, const float* __restrict__ bs_p,
    const int* __restrict__ slot, ushort* __restrict__ x1b)
{
    int pass = blockIdx.y;
    int sl = slot[pass];
    if (sl < 0) return;
    int s = pass >> 3, b = pass & 7;
    int och = blockIdx.x >> 4;                         // oc half: 0/1
    int tile = blockIdx.x & 15;
    int row0 = (tile >> 2) * 16, col0 = (tile & 3) * 16;

    __shared__ ushort wlds[2][2304 * 8];               // 2 x 36864 B
    __shared__ ushort xlds[3][1536 * 8];               // 3 x 24576 B (1296 real + pad)
                                                       // total 144 KB -> 1 block/CU

    int tid = threadIdx.x;
    int wv = tid >> 6, lane = tid & 63;
    int ks = lane >> 4, c = lane & 15;

    const ushort* xb_b = xbp + (size_t)b * 66 * 66 * 256;
    const ushort* wslab = wtb + (size_t)(s * 2 + och) * (8 * 18432);

    // per-thread x staging source offsets; 6 uniform issues/thread (vmcnt discipline)
    int goff[6];
#pragma unroll
    for (int it = 0; it < 6; ++it) {
        int k = it * 256 + tid;                        // granule 0..1535
        if (k < 1296) {
            int r = k / 72, rem = k % 72, ks2 = rem / 18, c2 = rem % 18;
            goff[it] = ((row0 + r) * 66 + (col0 + c2)) * 256 + ks2 * 8;
        } else {
            goff[it] = 0;                              // pad granule: any valid src
        }
    }
    int lds_us = wv * 512;                             // wave-uniform LDS base/it (us)

    f32x4 acc[4][4];
#pragma unroll
    for (int m = 0; m < 4; ++m)
#pragma unroll
        for (int n = 0; n < 4; ++n) acc[m][n] = (f32x4){0.f, 0.f, 0.f, 0.f};

    int Sb = 4 * wv * 72 + ks * 18 + c;                // B-granule base index

#define STAGE_W(ch, buf)                                                        \
    {                                                                           \
        const ushort* wsrc_ = wslab + (ch) * 18432;                             \
        _Pragma("unroll")                                                       \
        for (int it = 0; it < 9; ++it)                                          \
            gload16(wsrc_ + (size_t)(it * 256 + tid) * 8,                       \
                    &wlds[buf][(size_t)(it * 2048 + lds_us)]);                  \
    }
#define STAGE_X(ch, buf)                                                        \
    {                                                                           \
        const ushort* xsrc_ = xb_b + (ch) * 32;                                 \
        _Pragma("unroll")                                                       \
        for (int it = 0; it < 6; ++it)                                          \
            gload16(xsrc_ + goff[it], &xlds[buf][(size_t)(it * 2048 + lds_us)]);\
    }
#define PIPE_BARRIER(N)                                                         \
    asm volatile("s_waitcnt vmcnt(" #N ")" ::: "memory");                       \
    __builtin_amdgcn_sched_barrier(0);                                          \
    __builtin_amdgcn_s_barrier();                                               \
    __builtin_amdgcn_sched_barrier(0);

    // ---- prologue: w(0), x(0), x(1) in flight; drain w(0)+x(0), keep x(1) ----
    STAGE_W(0, 0);
    STAGE_X(0, 0);
    STAGE_X(1, 1);
    PIPE_BARRIER(6)

    int wcur = 0;
    for (int ch = 0; ch < 8; ++ch) {
        if (ch < 7) STAGE_W(ch + 1, wcur ^ 1);         // 9 gloads (drained this iter)
        if (ch < 6) STAGE_X(ch + 2, (ch + 2) % 3);     // 6 gloads (stay in flight)

        const ushort* wl = &wlds[wcur][0];
        const ushort* xl = &xlds[ch % 3][0];
#pragma unroll
        for (int kh = 0; kh < 3; ++kh) {
#pragma unroll
            for (int kw = 0; kw < 3; ++kw) {
                int tap = kh * 3 + kw;
                bf16x8 afr[4];
#pragma unroll
                for (int m = 0; m < 4; ++m)            // A: [tap][ks][oc] contiguous/quarter
                    afr[m] = ld_frag(wl + ((size_t)((tap * 4 + ks) * 64) + m * 16 + c) * 8);
#pragma unroll
                for (int n = 0; n < 4; ++n) {
                    bf16x8 bfr = ld_frag(xl + (size_t)(Sb + (n + kh) * 72 + kw) * 8);
#pragma unroll
                    for (int m = 0; m < 4; ++m)
                        acc[m][n] = __builtin_amdgcn_mfma_f32_16x16x32_bf16(
                            afr[m], bfr, acc[m][n], 0, 0, 0);
                }
            }
        }
        if (ch < 6) {
            PIPE_BARRIER(6)                            // drain x(ch+1)+w(ch+1)
        } else if (ch == 6) {
            PIPE_BARRIER(0)                            // tail: drain all
        }
        wcur ^= 1;
    }
#undef STAGE_W
#undef STAGE_X
#undef PIPE_BARRIER

    // ---- epilogue: BN + SiLU, bf16 store ----
    const float* scale = (s < 4) ? (se_p + s * ICH) : ss_p;
    const float* shift = (s < 4) ? (be_p + s * ICH) : bs_p;
    ushort* outp = x1b + (size_t)sl * (ICH * NPIX);
    int colg = col0 + c;
#pragma unroll
    for (int m = 0; m < 4; ++m) {
#pragma unroll
        for (int n = 0; n < 4; ++n) {
            int rowg = row0 + 4 * wv + n;
#pragma unroll
            for (int j = 0; j < 4; ++j) {
                int oc = och * 64 + m * 16 + ks * 4 + j;   // D: row=(lane>>4)*4+reg
                float v = acc[m][n][j] * scale[oc] + shift[oc];
                outp[(size_t)oc * NPIX + rowg * 64 + colg] = f2bf(silu_f(v));
            }
        }
    }
}

// ---------------- K5: depthwise 3x3 + BN + SiLU + weighted combine -> out ------------
__global__ __launch_bounds__(256) void k_cheap(
    const ushort* __restrict__ x1b, const float* __restrict__ We_c,
    const float* __restrict__ se_c, const float* __restrict__ be_c,
    const float* __restrict__ Ws_c, const float* __restrict__ ss_c,
    const float* __restrict__ bs_c, const float* __restrict__ wfull,
    const int* __restrict__ slot, float* __restrict__ out)
{
    int blk = blockIdx.x;
    int b = blk >> 7, c = blk & 127;
    __shared__ float img[3][66][66];                   // 52.3 KB -> 3 blocks/CU
    int tid = threadIdx.x;

    int nact = 0;
    int sls[3], sidx[3];
    float wgts[3];
    for (int s = 0; s < 5; ++s) {
        int sl = slot[s * 8 + b];
        if (sl < 0) continue;
        sls[nact] = sl; sidx[nact] = s;
        wgts[nact] = (s < 4) ? wfull[b * 5 + s] : 1.0f;
        ++nact;
    }

    for (int k = tid; k < 3 * 66 * 66; k += 256) ((float*)img)[k] = 0.f;
    __syncthreads();

#pragma unroll
    for (int a = 0; a < 3; ++a) {
        if (a < nact) {
            const ushort* src = x1b + ((size_t)sls[a] * ICH + c) * NPIX;
            for (int k = tid; k < 1024; k += 256) {
                int i = k >> 4, jc = (k & 15) * 4;
                uint2 u = *(const uint2*)(src + i * 64 + jc);
                img[a][1 + i][1 + jc] = bf2f((unsigned short)(u.x & 0xFFFFu));
                img[a][1 + i][2 + jc] = bf2f((unsigned short)(u.x >> 16));
                img[a][1 + i][3 + jc] = bf2f((unsigned short)(u.y & 0xFFFFu));
                img[a][1 + i][4 + jc] = bf2f((unsigned short)(u.y >> 16));
            }
        }
    }
    __syncthreads();

    float o1[16], o2[16];
#pragma unroll
    for (int t = 0; t < 16; ++t) { o1[t] = 0.f; o2[t] = 0.f; }

#pragma unroll
    for (int a = 0; a < 3; ++a) {
        if (a < nact) {
            int s = sidx[a];
            const float* wp = (s < 4) ? (We_c + (size_t)(s * ICH + c) * 9)
                                      : (Ws_c + (size_t)c * 9);
            float wc0 = wp[0], wc1 = wp[1], wc2 = wp[2], wc3 = wp[3], wc4 = wp[4],
                  wc5 = wp[5], wc6 = wp[6], wc7 = wp[7], wc8 = wp[8];
            float sc = (s < 4) ? se_c[s * ICH + c] : ss_c[c];
            float sh = (s < 4) ? be_c[s * ICH + c] : bs_c[c];
            float wgt = wgts[a];
#pragma unroll
            for (int t = 0; t < 16; ++t) {
                int p = tid + t * 256;
                int i = p >> 6, j = p & 63;
                float center = img[a][1 + i][1 + j];
                float d = wc0 * img[a][i][j];
                d = fmaf(wc1, img[a][i][j + 1], d);
                d = fmaf(wc2, img[a][i][j + 2], d);
                d = fmaf(wc3, img[a][i + 1][j], d);
                d = fmaf(wc4, center, d);
                d = fmaf(wc5, img[a][i + 1][j + 2], d);
                d = fmaf(wc6, img[a][i + 2][j], d);
                d = fmaf(wc7, img[a][i + 2][j + 1], d);
                d = fmaf(wc8, img[a][i + 2][j + 2], d);
                float v = d * sc + sh;
                o1[t] += wgt * center;
                o2[t] += wgt * silu_f(v);
            }
        }
    }

    float* out1 = out + ((size_t)(b * 256) + c) * NPIX;
    float* out2 = out + ((size_t)(b * 256) + 128 + c) * NPIX;
#pragma unroll
    for (int t = 0; t < 16; ++t) {
        int p = tid + t * 256;
        out1[p] = o1[t];
        out2[p] = o2[t];
    }
}

// ---------------- launcher ----------------
extern "C" void kernel_launch(void* const* d_in, const int* in_sizes, int n_in,
                              void* d_out, int out_size, void* d_ws, size_t ws_size,
                              hipStream_t stream)
{
    const float* x    = (const float*)d_in[0];
    const float* Wr1  = (const float*)d_in[1];
    const float* sr1  = (const float*)d_in[2];
    const float* br1  = (const float*)d_in[3];
    const float* Wr2  = (const float*)d_in[4];
    const float* sr2  = (const float*)d_in[5];
    const float* br2  = (const float*)d_in[6];
    const float* We_p = (const float*)d_in[7];
    const float* se_p = (const float*)d_in[8];
    const float* be_p = (const float*)d_in[9];
    const float* We_c = (const float*)d_in[10];
    const float* se_c = (const float*)d_in[11];
    const float* be_c = (const float*)d_in[12];
    const float* Ws_p = (const float*)d_in[13];
    const float* ss_p = (const float*)d_in[14];
    const float* bs_p = (const float*)d_in[15];
    const float* Ws_c = (const float*)d_in[16];
    const float* ss_c = (const float*)d_in[17];
    const float* bs_c = (const float*)d_in[18];
    const int*  topk  = (const int*)d_in[19];
    float* out = (float*)d_out;
    float* ws  = (float*)d_ws;

    float*  xd    = ws + OFF_XD;
    float*  hmean = ws + OFF_HMEAN;
    float*  wfull = ws + OFF_WFULL;
    int*    slot  = (int*)(ws + OFF_SLOT);
    ushort* wtb   = (ushort*)(ws + OFF_WTB);
    ushort* xbp   = (ushort*)(ws + OFF_XBP);
    ushort* x1b   = (ushort*)(ws + OFF_X1B);
    // requires ws_size >= 48.1 MB (round 3 proved >= 58.3 MB works)

    hipMemsetAsync(xbp, 0, (size_t)8 * 66 * 66 * 256 * sizeof(ushort), stream);
    k_avgpool<<<512, 256, 0, stream>>>(x, xd);
    k_xprep<<<512, 256, 0, stream>>>(x, xbp);
    k_wprep16<<<5760, 256, 0, stream>>>(We_p, Ws_p, wtb);
    k_router_conv<<<256, 256, 0, stream>>>(xd, Wr1, sr1, br1, hmean);
    k_router_final<<<1, 64, 0, stream>>>(hmean, Wr2, sr2, br2, topk, wfull, slot);
    k_primary_mfma<<<dim3(32, 40), 256, 0, stream>>>(xbp, wtb, se_p, be_p, ss_p, bs_p, slot, x1b);
    k_cheap<<<1024, 256, 0, stream>>>(x1b, We_c, se_c, be_c, Ws_c, ss_c, bs_c, wfull, slot, out);
}